// Round 13
// baseline (4892.393 us; speedup 1.0000x reference)
//
#include <hip/hip_runtime.h>
#include <hip/hip_bf16.h>
#include <float.h>

#define NB 64
#define HD 1024
#define H3 3072
#define NC6 6144
#define NV 32000
#define TSTEPS 32
#define LBLK 500        // logits blocks (64 cols each)
#define NSLICE 8        // select2 col slices
#define GKS 4           // gates K-split
#define NKT 16          // K=1024 / 64 per staging step
#define MARGIN_COEF 0.010f
#define MARGIN_ABS  1e-3f
#define MAXCAND 1024

using bf16x8 = __attribute__((ext_vector_type(8))) short;
using f32x4  = __attribute__((ext_vector_type(4))) float;
using s16x4  = __attribute__((ext_vector_type(4))) short;

__device__ __forceinline__ float sigmoidf_(float x) {
    return 1.0f / (1.0f + expf(-x));
}
__device__ __forceinline__ float dot4(float4 h, float4 w, float a) {
    return fmaf(h.w, w.w, fmaf(h.z, w.z, fmaf(h.y, w.y, fmaf(h.x, w.x, a))));
}
__device__ __forceinline__ short bf16bits(float x) {
    __hip_bfloat16 b = __float2bfloat16(x);
    return __builtin_bit_cast(short, b);
}
__device__ __forceinline__ unsigned ordbits(float v) {
    unsigned u = __float_as_uint(v);
    return (u & 0x80000000u) ? ~u : (u | 0x80000000u);
}
__device__ __forceinline__ float invord(unsigned e) {
    unsigned u = (e & 0x80000000u) ? (e ^ 0x80000000u) : ~e;
    return __uint_as_float(u);
}

// ============ one-time: Wout -> Wbf (bf16) + wnorm ============
__global__ __launch_bounds__(256) void wbf_kernel(const float* __restrict__ W,
                                                  short* __restrict__ Wbf,
                                                  float* __restrict__ wnorm)
{
    int r = blockIdx.x, tdx = threadIdx.x;
    float4 v = *(const float4*)&W[(size_t)r * HD + tdx * 4];
    s16x4 p;
    p[0] = bf16bits(v.x); p[1] = bf16bits(v.y);
    p[2] = bf16bits(v.z); p[3] = bf16bits(v.w);
    *(s16x4*)(Wbf + (size_t)r * HD + tdx * 4) = p;
    float ss = v.x*v.x + v.y*v.y + v.z*v.z + v.w*v.w;
    #pragma unroll
    for (int off = 32; off; off >>= 1) ss += __shfl_xor(ss, off);
    __shared__ float red[4];
    if ((tdx & 63) == 0) red[tdx >> 6] = ss;
    __syncthreads();
    if (tdx == 0) wnorm[r] = sqrtf(red[0] + red[1] + red[2] + red[3]);
}

// ============ init: ht4/xt4 + Abf + hnorm + per-step resets ============
__global__ __launch_bounds__(256) void init_kernel(
    const float* __restrict__ zs, const float* __restrict__ cs,
    const float* __restrict__ emb,
    float4* __restrict__ ht4, float4* __restrict__ xt4,
    short* __restrict__ Abf, float* __restrict__ hnorm,
    unsigned* __restrict__ Tu, unsigned long long* __restrict__ best,
    int* __restrict__ done)
{
    int b = blockIdx.x;
    int kg = threadIdx.x;
    int j = kg * 4;
    float4 v;
    if (j < 512) v = *(const float4*)&zs[b * 512 + j];
    else         v = *(const float4*)&cs[b * 512 + (j - 512)];
    ht4[kg * NB + b] = v;
    xt4[kg * NB + b] = *(const float4*)&emb[HD + j];  // SOS = 1

    s16x4 p;
    p[0] = bf16bits(v.x); p[1] = bf16bits(v.y);
    p[2] = bf16bits(v.z); p[3] = bf16bits(v.w);
    *(s16x4*)(Abf + (size_t)b * HD + j) = p;

    float ss = v.x*v.x + v.y*v.y + v.z*v.z + v.w*v.w;
    #pragma unroll
    for (int off = 32; off; off >>= 1) ss += __shfl_xor(ss, off);
    __shared__ float red[4];
    if ((kg & 63) == 0) red[kg >> 6] = ss;
    __syncthreads();
    if (kg == 0) {
        hnorm[b] = sqrtf(red[0] + red[1] + red[2] + red[3]);
        Tu[b] = 0u;
        best[b] = 0ull;
        done[b] = 0;
    }
}

// ---- fp32 GEMV core (proven R7/R11 path, exact) ----
template<int NPAIR>
__device__ __forceinline__ void gemv_core(const float* __restrict__ wb,
                                          const float4* __restrict__ t4,
                                          int bl, float acc0[8], float acc1[8])
{
    float4 wc[8], wn[8], h0c, h1c, h0n, h1n;
    #pragma unroll
    for (int r = 0; r < 8; ++r) wc[r] = *(const float4*)&wb[(size_t)r * HD];
    h0c = t4[bl]; h1c = t4[bl + 32];

    #pragma unroll 1
    for (int p = 0; p < NPAIR - 1; ++p) {
        const float*  w1 = wb + (2 * p + 1) * 4;
        const float4* t1 = t4 + (size_t)(2 * p + 1) * NB;
        #pragma unroll
        for (int r = 0; r < 8; ++r) wn[r] = *(const float4*)&w1[(size_t)r * HD];
        h0n = t1[bl]; h1n = t1[bl + 32];
        #pragma unroll
        for (int r = 0; r < 8; ++r) {
            acc0[r] = dot4(h0c, wc[r], acc0[r]);
            acc1[r] = dot4(h1c, wc[r], acc1[r]);
        }
        const float*  w2 = wb + (2 * p + 2) * 4;
        const float4* t2 = t4 + (size_t)(2 * p + 2) * NB;
        #pragma unroll
        for (int r = 0; r < 8; ++r) wc[r] = *(const float4*)&w2[(size_t)r * HD];
        h0c = t2[bl]; h1c = t2[bl + 32];
        #pragma unroll
        for (int r = 0; r < 8; ++r) {
            acc0[r] = dot4(h0n, wn[r], acc0[r]);
            acc1[r] = dot4(h1n, wn[r], acc1[r]);
        }
    }
    const float*  w1 = wb + (2 * NPAIR - 1) * 4;
    const float4* t1 = t4 + (size_t)(2 * NPAIR - 1) * NB;
    #pragma unroll
    for (int r = 0; r < 8; ++r) wn[r] = *(const float4*)&w1[(size_t)r * HD];
    h0n = t1[bl]; h1n = t1[bl + 32];
    #pragma unroll
    for (int r = 0; r < 8; ++r) {
        acc0[r] = dot4(h0c, wc[r], acc0[r]);
        acc1[r] = dot4(h1c, wc[r], acc1[r]);
    }
    #pragma unroll
    for (int r = 0; r < 8; ++r) {
        acc0[r] = dot4(h0n, wn[r], acc0[r]);
        acc1[r] = dot4(h1n, wn[r], acc1[r]);
    }
}

// ============ gates GEMV, K-split 4, gpart[ks][b][6144] (R11 exact path) ============
__global__ __launch_bounds__(256) void gates_gemv(
    const float4* __restrict__ xt4, const float4* __restrict__ ht4,
    const float* __restrict__ Wih, const float* __restrict__ Whh,
    float* __restrict__ gpart)
{
    int cg = blockIdx.x >> 2;
    int ks = blockIdx.x & 3;
    int tid = threadIdx.x, wid = tid >> 6, lane = tid & 63;
    int bl = lane & 31, ch = lane >> 5;
    int c0 = cg * 64 + wid * 16 + ch * 8;
    bool isH = c0 >= H3;
    const float4* __restrict__ t4 = (isH ? ht4 : xt4) + (size_t)ks * 64 * NB;
    const float* __restrict__ W   = isH ? Whh : Wih;
    const float* __restrict__ wb  = W + (size_t)(c0 - (isH ? H3 : 0)) * HD + ks * 256;

    float acc0[8] = {}, acc1[8] = {};
    gemv_core<32>(wb, t4, bl, acc0, acc1);

    float* g0 = gpart + (size_t)(ks * NB + bl) * NC6 + c0;
    float* g1 = gpart + (size_t)(ks * NB + bl + 32) * NC6 + c0;
    *(float4*)(g0)     = make_float4(acc0[0], acc0[1], acc0[2], acc0[3]);
    *(float4*)(g0 + 4) = make_float4(acc0[4], acc0[5], acc0[6], acc0[7]);
    *(float4*)(g1)     = make_float4(acc1[0], acc1[1], acc1[2], acc1[3]);
    *(float4*)(g1 + 4) = make_float4(acc1[4], acc1[5], acc1[6], acc1[7]);
}

// ============ GRU fuse + habf epilogue + per-step resets ============
__global__ __launch_bounds__(256) void gru_fuse(
    const float* __restrict__ gpart,
    const float* __restrict__ bih, const float* __restrict__ bhh,
    float4* __restrict__ ht4, short* __restrict__ Abf,
    float* __restrict__ hnorm, unsigned* __restrict__ Tu,
    unsigned long long* __restrict__ best, int* __restrict__ done)
{
    int b = blockIdx.x;
    int kg = threadIdx.x;
    int j0 = kg * 4;
    float4 ir = {}, iz = {}, in_ = {}, hr = {}, hz = {}, hn = {};
    #pragma unroll
    for (int ks = 0; ks < GKS; ++ks) {
        const float* g = gpart + (size_t)(ks * NB + b) * NC6;
        float4 a;
        a = *(const float4*)&g[j0];             ir.x+=a.x; ir.y+=a.y; ir.z+=a.z; ir.w+=a.w;
        a = *(const float4*)&g[HD + j0];        iz.x+=a.x; iz.y+=a.y; iz.z+=a.z; iz.w+=a.w;
        a = *(const float4*)&g[2*HD + j0];      in_.x+=a.x; in_.y+=a.y; in_.z+=a.z; in_.w+=a.w;
        a = *(const float4*)&g[H3 + j0];        hr.x+=a.x; hr.y+=a.y; hr.z+=a.z; hr.w+=a.w;
        a = *(const float4*)&g[H3 + HD + j0];   hz.x+=a.x; hz.y+=a.y; hz.z+=a.z; hz.w+=a.w;
        a = *(const float4*)&g[H3 + 2*HD + j0]; hn.x+=a.x; hn.y+=a.y; hn.z+=a.z; hn.w+=a.w;
    }
    float4 vbi0 = *(const float4*)&bih[j0];
    float4 vbi1 = *(const float4*)&bih[HD + j0];
    float4 vbi2 = *(const float4*)&bih[2*HD + j0];
    float4 vbh0 = *(const float4*)&bhh[j0];
    float4 vbh1 = *(const float4*)&bhh[HD + j0];
    float4 vbh2 = *(const float4*)&bhh[2*HD + j0];
    float4 hv = ht4[kg * NB + b];
    float irv[4] = {ir.x+vbi0.x, ir.y+vbi0.y, ir.z+vbi0.z, ir.w+vbi0.w};
    float izv[4] = {iz.x+vbi1.x, iz.y+vbi1.y, iz.z+vbi1.z, iz.w+vbi1.w};
    float inv[4] = {in_.x+vbi2.x, in_.y+vbi2.y, in_.z+vbi2.z, in_.w+vbi2.w};
    float hrv[4] = {hr.x+vbh0.x, hr.y+vbh0.y, hr.z+vbh0.z, hr.w+vbh0.w};
    float hzv[4] = {hz.x+vbh1.x, hz.y+vbh1.y, hz.z+vbh1.z, hz.w+vbh1.w};
    float hnv[4] = {hn.x+vbh2.x, hn.y+vbh2.y, hn.z+vbh2.z, hn.w+vbh2.w};
    float hvv[4] = {hv.x, hv.y, hv.z, hv.w};
    float o[4];
    #pragma unroll
    for (int u = 0; u < 4; ++u) {
        float r = sigmoidf_(irv[u] + hrv[u]);
        float z = sigmoidf_(izv[u] + hzv[u]);
        float n = tanhf(inv[u] + r * hnv[u]);
        o[u] = (1.0f - z) * n + z * hvv[u];
    }
    ht4[kg * NB + b] = make_float4(o[0], o[1], o[2], o[3]);

    // habf epilogue: bf16 row-major + hnorm + resets
    s16x4 p;
    p[0] = bf16bits(o[0]); p[1] = bf16bits(o[1]);
    p[2] = bf16bits(o[2]); p[3] = bf16bits(o[3]);
    *(s16x4*)(Abf + (size_t)b * HD + j0) = p;

    float ss = o[0]*o[0] + o[1]*o[1] + o[2]*o[2] + o[3]*o[3];
    #pragma unroll
    for (int off = 32; off; off >>= 1) ss += __shfl_xor(ss, off);
    __shared__ float red[4];
    if ((kg & 63) == 0) red[kg >> 6] = ss;
    __syncthreads();
    if (kg == 0) {
        hnorm[b] = sqrtf(red[0] + red[1] + red[2] + red[3]);
        Tu[b] = 0u;
        best[b] = 0ull;
        done[b] = 0;
    }
}

// ============ logits screen: bf16 MFMA -> lb; fused T via atomicMax ============
__global__ __launch_bounds__(256, 2) void logits_lb(
    const short* __restrict__ Abf, const short* __restrict__ Wbf,
    const float* __restrict__ bout, const float* __restrict__ wnorm,
    const float* __restrict__ hnorm,
    float* __restrict__ lb, unsigned* __restrict__ Tu)
{
    __shared__ __align__(16) char tile[2][16384];
    __shared__ float smax[64][4];

    const int tid = threadIdx.x;
    const int wv = tid >> 6, l = tid & 63;
    const int blk = blockIdx.x;

    const short* srows[4];
    int lof[4];
    #pragma unroll
    for (int i = 0; i < 4; ++i) {
        int slot = i * 256 + tid;
        int row = slot >> 3;
        int kb  = (slot & 7) * 16;
        const short* g = (row < 64)
            ? (Abf + (size_t)row * HD)
            : (Wbf + ((size_t)(blk * 64 + (row - 64))) * HD);
        srows[i] = g + (kb >> 1);
        lof[i] = row * 128 + (kb ^ ((row & 7) << 4));
    }

    int a_off[4][2], b_off[2];
    #pragma unroll
    for (int m = 0; m < 4; ++m)
        #pragma unroll
        for (int kf = 0; kf < 2; ++kf) {
            int row = m * 16 + (l & 15);
            int kb = kf * 64 + (l >> 4) * 16;
            a_off[m][kf] = row * 128 + (kb ^ ((row & 7) << 4));
        }
    #pragma unroll
    for (int kf = 0; kf < 2; ++kf) {
        int row = 64 + wv * 16 + (l & 15);
        int kb = kf * 64 + (l >> 4) * 16;
        b_off[kf] = row * 128 + (kb ^ ((row & 7) << 4));
    }

    float4 rg[4];
    #pragma unroll
    for (int i = 0; i < 4; ++i) rg[i] = *(const float4*)(srows[i]);

    f32x4 acc[4] = {};

    int cur = 0;
    #pragma unroll 1
    for (int kt = 0; kt < NKT; ++kt) {
        char* buf = tile[cur];
        #pragma unroll
        for (int i = 0; i < 4; ++i) *(float4*)(buf + lof[i]) = rg[i];
        __syncthreads();
        if (kt < NKT - 1) {
            #pragma unroll
            for (int i = 0; i < 4; ++i)
                rg[i] = *(const float4*)(srows[i] + (size_t)(kt + 1) * 64);
        }
        #pragma unroll
        for (int kf = 0; kf < 2; ++kf) {
            bf16x8 bfrag = *(const bf16x8*)(buf + b_off[kf]);
            #pragma unroll
            for (int m = 0; m < 4; ++m) {
                bf16x8 afrag = *(const bf16x8*)(buf + a_off[m][kf]);
                acc[m] = __builtin_amdgcn_mfma_f32_16x16x32_bf16(afrag, bfrag, acc[m], 0, 0, 0);
            }
        }
        cur ^= 1;
        __syncthreads();
    }

    int col = blk * 64 + wv * 16 + (l & 15);
    float bo = bout[col];
    float wn = wnorm[col];
    float selmax = -FLT_MAX;
    int pick = l & 15;
    #pragma unroll
    for (int m = 0; m < 4; ++m) {
        #pragma unroll
        for (int j = 0; j < 4; ++j) {
            int row = m * 16 + (l >> 4) * 4 + j;
            float lbv = acc[m][j] + bo;
            lb[(size_t)row * NV + col] = lbv;
            float low = lbv - (MARGIN_COEF * hnorm[row] * wn + MARGIN_ABS);
            #pragma unroll
            for (int mask = 1; mask <= 8; mask <<= 1)
                low = fmaxf(low, __shfl_xor(low, mask, 64));
            if (pick == m * 4 + j) selmax = low;
        }
    }
    int row = ((l & 15) >> 2) * 16 + (l >> 4) * 4 + (l & 3);
    smax[row][wv] = selmax;
    __syncthreads();
    if (wv == 0) {
        float v = fmaxf(fmaxf(smax[l][0], smax[l][1]), fmaxf(smax[l][2], smax[l][3]));
        atomicMax(&Tu[l], ordbits(v));
    }
}

// ============ select + exact rescore + commit; last block per b gathers ============
__global__ __launch_bounds__(256) void select2_kernel(
    const float* __restrict__ lb, const float* __restrict__ wnorm,
    const float* __restrict__ hnorm, const unsigned* __restrict__ Tu,
    const float* __restrict__ Wout, const float* __restrict__ bout,
    const float4* __restrict__ ht4, const float* __restrict__ emb,
    unsigned long long* __restrict__ best, int* __restrict__ done,
    int* __restrict__ resps, int t, float4* __restrict__ xt4)
{
    int b = blockIdx.x >> 3, slice = blockIdx.x & 7;
    int tid = threadIdx.x, wv = tid >> 6;
    const float* lbr = lb + (size_t)b * NV;
    float coef = MARGIN_COEF * hnorm[b];
    float tb = invord(Tu[b]);

    __shared__ int scount;
    __shared__ int cand[MAXCAND];
    __shared__ float rsum[4];
    __shared__ int lastflag;
    __shared__ unsigned long long kbest;

    if (tid == 0) scount = 0;
    __syncthreads();

    int c0 = slice * (NV / NSLICE);
    for (int c = c0 + tid; c < c0 + NV / NSLICE; c += 256) {
        if (lbr[c] + (coef * wnorm[c] + MARGIN_ABS) >= tb) {
            int s = atomicAdd(&scount, 1);
            if (s < MAXCAND) cand[s] = c;
        }
    }
    __syncthreads();
    int n = scount < MAXCAND ? scount : MAXCAND;

    float4 h4 = ht4[tid * NB + b];
    for (int s = 0; s < n; ++s) {
        int c = cand[s];
        float4 w4 = *(const float4*)&Wout[(size_t)c * HD + tid * 4];
        float p = dot4(h4, w4, 0.0f);
        #pragma unroll
        for (int off = 32; off; off >>= 1) p += __shfl_xor(p, off);
        if ((tid & 63) == 0) rsum[wv] = p;
        __syncthreads();
        if (tid == 0) {
            float tot = rsum[0] + rsum[1] + rsum[2] + rsum[3] + bout[c];
            unsigned long long key =
                ((unsigned long long)ordbits(tot) << 32) | (unsigned)(~c);
            atomicMax(&best[b], key);
        }
        __syncthreads();
    }

    // completion protocol: last finished slice for this b does the gather
    __threadfence();
    if (tid == 0) {
        int old = atomicAdd(&done[b], 1);
        lastflag = (old == NSLICE - 1);
    }
    __syncthreads();
    if (lastflag) {
        if (tid == 0) {
            __threadfence();
            kbest = atomicMax(&best[b], 0ull);   // coherent read
        }
        __syncthreads();
        int tok = ~(unsigned)(kbest & 0xFFFFFFFFull);
        if (tid == 0) resps[b * TSTEPS + t] = tok;
        xt4[tid * NB + b] = *(const float4*)&emb[(size_t)tok * HD + tid * 4];
    }
}

// ================= fallback fp32 logits path (used only if ws too small) =================
__global__ __launch_bounds__(256) void logits_gemv(
    const float4* __restrict__ ht4, const float* __restrict__ Wout,
    const float* __restrict__ bout,
    float* __restrict__ bval, int* __restrict__ bidx)
{
    int tid = threadIdx.x, wid = tid >> 6, lane = tid & 63;
    int bl = lane & 31, ch = lane >> 5;
    int c0 = blockIdx.x * 64 + wid * 16 + ch * 8;
    const float* __restrict__ wb = Wout + (size_t)c0 * HD;

    float acc0[8] = {}, acc1[8] = {};
    gemv_core<128>(wb, ht4, bl, acc0, acc1);

    float bv0 = -FLT_MAX, bv1 = -FLT_MAX; int bi0 = 0, bi1 = 0;
    #pragma unroll
    for (int r = 0; r < 8; ++r) {
        float bo = bout[c0 + r];
        float v0 = acc0[r] + bo;
        float v1 = acc1[r] + bo;
        if (v0 > bv0) { bv0 = v0; bi0 = c0 + r; }
        if (v1 > bv1) { bv1 = v1; bi1 = c0 + r; }
    }
    __shared__ float sv[NB][8];
    __shared__ int   si[NB][8];
    int slot = wid * 2 + ch;
    sv[bl][slot] = bv0;      si[bl][slot] = bi0;
    sv[bl + 32][slot] = bv1; si[bl + 32][slot] = bi1;
    __syncthreads();
    if (wid == 0) {
        float bv = sv[lane][0]; int bi = si[lane][0];
        #pragma unroll
        for (int s = 1; s < 8; ++s) {
            float v = sv[lane][s];
            if (v > bv) { bv = v; bi = si[lane][s]; }
        }
        bval[(size_t)lane * LBLK + blockIdx.x] = bv;
        bidx[(size_t)lane * LBLK + blockIdx.x] = bi;
    }
}

__global__ __launch_bounds__(512) void argmax_reduce_gather(
    const float* __restrict__ bval, const int* __restrict__ bidx,
    const float* __restrict__ emb, int* __restrict__ resps, int t,
    float4* __restrict__ xt4)
{
    int b = blockIdx.x;
    int tid = threadIdx.x;
    float bv = -FLT_MAX; int bi = 0x7fffffff;
    if (tid < LBLK) { bv = bval[(size_t)b * LBLK + tid]; bi = bidx[(size_t)b * LBLK + tid]; }
    for (int off = 32; off > 0; off >>= 1) {
        float ov = __shfl_down(bv, off);
        int   oi = __shfl_down(bi, off);
        if (ov > bv || (ov == bv && oi < bi)) { bv = ov; bi = oi; }
    }
    __shared__ float sv[8];
    __shared__ int   si[8];
    __shared__ int   stok;
    int wid = tid >> 6;
    if ((tid & 63) == 0) { sv[wid] = bv; si[wid] = bi; }
    __syncthreads();
    if (tid == 0) {
        bv = sv[0]; bi = si[0];
        #pragma unroll
        for (int w = 1; w < 8; ++w)
            if (sv[w] > bv || (sv[w] == bv && si[w] < bi)) { bv = sv[w]; bi = si[w]; }
        stok = bi;
        resps[b * TSTEPS + t] = bi;
    }
    __syncthreads();
    if (tid < 256) {
        int tok = stok;
        xt4[tid * NB + b] = *(const float4*)&emb[(size_t)tok * HD + tid * 4];
    }
}

// ---------------- resp_lens ----------------
__global__ void resp_lens_kernel(const int* __restrict__ resps, int* __restrict__ lens)
{
    int b = threadIdx.x;
    if (b >= NB) return;
    int len = TSTEPS + 1;
    for (int t = TSTEPS - 1; t >= 0; t--)
        if (resps[b * TSTEPS + t] == 2) len = t + 1;
    lens[b] = len;
}

extern "C" void kernel_launch(void* const* d_in, const int* in_sizes, int n_in,
                              void* d_out, int out_size, void* d_ws, size_t ws_size,
                              hipStream_t stream) {
    const float* zs   = (const float*)d_in[0];
    const float* cs   = (const float*)d_in[1];
    const float* emb  = (const float*)d_in[2];
    const float* Wih  = (const float*)d_in[3];
    const float* Whh  = (const float*)d_in[4];
    const float* bih  = (const float*)d_in[5];
    const float* bhh  = (const float*)d_in[6];
    const float* Wout = (const float*)d_in[7];
    const float* bout = (const float*)d_in[8];
    int* out = (int*)d_out;  // [64*32 resps][64 lens], int32

    char* ws = (char*)d_ws;
    float4* xt4  = (float4*)ws; ws += (size_t)256 * NB * 16;          // 256 KB
    float4* ht4  = (float4*)ws; ws += (size_t)256 * NB * 16;          // 256 KB
    float*  gpart = (float*)ws; ws += (size_t)GKS * NB * NC6 * 4;     // 6.3 MB
    float*  bval = (float*)ws;  ws += (size_t)NB * LBLK * 4;          // 128 KB
    int*    bidx = (int*)ws;    ws += (size_t)NB * LBLK * 4;          // 128 KB
    short*  Abf  = (short*)ws;  ws += (size_t)NB * HD * 2;            // 128 KB
    float*  wnorm = (float*)ws; ws += (size_t)NV * 4;                 // 128 KB
    float*  hnorm = (float*)ws; ws += 256;
    unsigned* Tu = (unsigned*)ws; ws += 256;
    unsigned long long* best = (unsigned long long*)ws; ws += NB * 8;
    int*    done = (int*)ws;    ws += 256;
    float*  lb   = (float*)ws;  ws += (size_t)NB * NV * 4;            // 8.2 MB
    short*  Wbf  = (short*)ws;  ws += (size_t)NV * HD * 2;            // 65.5 MB
    size_t needed = (size_t)(ws - (char*)d_ws);
    bool use_bf16 = ws_size >= needed;

    if (use_bf16) wbf_kernel<<<NV, 256, 0, stream>>>(Wout, Wbf, wnorm);
    init_kernel<<<NB, 256, 0, stream>>>(zs, cs, emb, ht4, xt4, Abf, hnorm, Tu, best, done);
    for (int t = 0; t < TSTEPS; t++) {
        gates_gemv<<<96 * GKS, 256, 0, stream>>>(xt4, ht4, Wih, Whh, gpart);
        gru_fuse<<<NB, 256, 0, stream>>>(gpart, bih, bhh, ht4, Abf, hnorm, Tu, best, done);
        if (use_bf16) {
            logits_lb<<<LBLK, 256, 0, stream>>>(Abf, Wbf, bout, wnorm, hnorm, lb, Tu);
            select2_kernel<<<NB * NSLICE, 256, 0, stream>>>(lb, wnorm, hnorm, Tu, Wout, bout,
                                                            ht4, emb, best, done, out, t, xt4);
        } else {
            logits_gemv<<<LBLK, 256, 0, stream>>>(ht4, Wout, bout, bval, bidx);
            argmax_reduce_gather<<<NB, 512, 0, stream>>>(bval, bidx, emb, out, t, xt4);
        }
    }
    resp_lens_kernel<<<1, 64, 0, stream>>>(out, out + NB * TSTEPS);
}

// Round 14
// 3342.651 us; speedup vs baseline: 1.4636x; 1.4636x over previous
//
#include <hip/hip_runtime.h>
#include <hip/hip_bf16.h>
#include <float.h>

#define NB 64
#define HD 1024
#define H3 3072
#define NC6 6144
#define NV 32000
#define TSTEPS 32
#define LBLK 500        // logits blocks (64 cols each)
#define BML 512         // bmlow stride (>= LBLK)
#define NSLICE 8        // select2 col slices
#define NKT 16          // 16 K-steps of 64 per GEMM kernel
#define MARGIN_COEF 0.010f
#define MARGIN_ABS  1e-3f
#define MAXCAND 1024

using bf16x8 = __attribute__((ext_vector_type(8))) short;
using f32x4  = __attribute__((ext_vector_type(4))) float;
using s16x4  = __attribute__((ext_vector_type(4))) short;

__device__ __forceinline__ float sigmoidf_(float x) {
    return 1.0f / (1.0f + expf(-x));
}
__device__ __forceinline__ float dot4(float4 h, float4 w, float a) {
    return fmaf(h.w, w.w, fmaf(h.z, w.z, fmaf(h.y, w.y, fmaf(h.x, w.x, a))));
}
__device__ __forceinline__ short bf16bits(float x) {
    __hip_bfloat16 b = __float2bfloat16(x);
    return __builtin_bit_cast(short, b);
}
__device__ __forceinline__ float bf16val(short s) {
    __hip_bfloat16 b = __builtin_bit_cast(__hip_bfloat16, s);
    return __bfloat162float(b);
}
__device__ __forceinline__ unsigned ordbits(float v) {
    unsigned u = __float_as_uint(v);
    return (u & 0x80000000u) ? ~u : (u | 0x80000000u);
}

// ============ one-time: Wih/Whh -> 2-way split [row][2048] = [w1|w2] ============
__global__ __launch_bounds__(256) void wsplit2_kernel(
    const float* __restrict__ Wih, const float* __restrict__ Whh,
    short* __restrict__ WihSp, short* __restrict__ WhhSp)
{
    int r = blockIdx.x;             // 0..6143
    const float* src = (r < H3) ? &Wih[(size_t)r * HD] : &Whh[(size_t)(r - H3) * HD];
    short* dst = (r < H3) ? &WihSp[(size_t)r * 2048] : &WhhSp[(size_t)(r - H3) * 2048];
    int k = threadIdx.x * 4;
    float4 v = *(const float4*)&src[k];
    float xs[4] = {v.x, v.y, v.z, v.w};
    s16x4 p1, p2;
    #pragma unroll
    for (int e = 0; e < 4; ++e) {
        short s1 = bf16bits(xs[e]);
        short s2 = bf16bits(xs[e] - bf16val(s1));
        p1[e] = s1; p2[e] = s2;
    }
    *(s16x4*)(dst + k)        = p1;
    *(s16x4*)(dst + 1024 + k) = p2;
}

// ============ one-time: Wout -> Wbf (bf16) + wnorm ============
__global__ __launch_bounds__(256) void wbf_kernel(const float* __restrict__ W,
                                                  short* __restrict__ Wbf,
                                                  float* __restrict__ wnorm)
{
    int r = blockIdx.x, tdx = threadIdx.x;
    float4 v = *(const float4*)&W[(size_t)r * HD + tdx * 4];
    s16x4 p;
    p[0] = bf16bits(v.x); p[1] = bf16bits(v.y);
    p[2] = bf16bits(v.z); p[3] = bf16bits(v.w);
    *(s16x4*)(Wbf + (size_t)r * HD + tdx * 4) = p;
    float ss = v.x*v.x + v.y*v.y + v.z*v.z + v.w*v.w;
    #pragma unroll
    for (int off = 32; off; off >>= 1) ss += __shfl_xor(ss, off);
    __shared__ float red[4];
    if ((tdx & 63) == 0) red[tdx >> 6] = ss;
    __syncthreads();
    if (tdx == 0) wnorm[r] = sqrtf(red[0] + red[1] + red[2] + red[3]);
}

// ============ init: ht4 + Hsp + Xsp + hnorm ============
__global__ __launch_bounds__(256) void init_kernel(
    const float* __restrict__ zs, const float* __restrict__ cs,
    const float* __restrict__ emb,
    float4* __restrict__ ht4, short* __restrict__ Hsp, short* __restrict__ Xsp,
    float* __restrict__ hnorm)
{
    int b = blockIdx.x;
    int kg = threadIdx.x;
    int j = kg * 4;
    float4 v;
    if (j < 512) v = *(const float4*)&zs[b * 512 + j];
    else         v = *(const float4*)&cs[b * 512 + (j - 512)];
    ht4[kg * NB + b] = v;
    float hs[4] = {v.x, v.y, v.z, v.w};
    s16x4 p1, p2;
    #pragma unroll
    for (int e = 0; e < 4; ++e) {
        short s1 = bf16bits(hs[e]);
        short s2 = bf16bits(hs[e] - bf16val(s1));
        p1[e] = s1; p2[e] = s2;
    }
    *(s16x4*)(Hsp + (size_t)b * 2048 + j)        = p1;
    *(s16x4*)(Hsp + (size_t)b * 2048 + 1024 + j) = p2;

    float4 x = *(const float4*)&emb[HD + j];  // SOS = 1
    float xs[4] = {x.x, x.y, x.z, x.w};
    #pragma unroll
    for (int e = 0; e < 4; ++e) {
        short s1 = bf16bits(xs[e]);
        short s2 = bf16bits(xs[e] - bf16val(s1));
        p1[e] = s1; p2[e] = s2;
    }
    *(s16x4*)(Xsp + (size_t)b * 2048 + j)        = p1;
    *(s16x4*)(Xsp + (size_t)b * 2048 + 1024 + j) = p2;

    float ss = hs[0]*hs[0] + hs[1]*hs[1] + hs[2]*hs[2] + hs[3]*hs[3];
    #pragma unroll
    for (int off = 32; off; off >>= 1) ss += __shfl_xor(ss, off);
    __shared__ float red[4];
    if ((kg & 63) == 0) red[kg >> 6] = ss;
    __syncthreads();
    if (kg == 0) hnorm[b] = sqrtf(red[0] + red[1] + red[2] + red[3]);
}

// ============ gates: 2-way-split full-product MFMA, K-split 4 (verified R12) ============
// grid 384: cg = blk>>2 (64 cols of 6144), ks = blk&3 (k'' slice of 1024).
// K''=4096 arranged A'=[a1|a2|a1|a2], W'=[w1|w1|w2|w2] -> all 4 cross terms.
__global__ __launch_bounds__(256, 2) void gates_mfma(
    const short* __restrict__ Xsp, const short* __restrict__ Hsp,
    const short* __restrict__ WihSp, const short* __restrict__ WhhSp,
    float* __restrict__ gpart)
{
    __shared__ __align__(16) char tile[2][16384];

    const int tid = threadIdx.x;
    const int wv = tid >> 6, l = tid & 63;
    int cg = blockIdx.x >> 2;
    int ks = blockIdx.x & 3;
    int c0 = cg * 64;
    bool isH = c0 >= H3;
    const short* __restrict__ Asrc = isH ? Hsp : Xsp;
    const short* __restrict__ Wsrc = isH ? WhhSp : WihSp;
    int wc0 = c0 - (isH ? H3 : 0);
    int k0 = ks * 1024;
    int ka0 = (k0 & 1023) + (((k0 >> 10) & 1) << 10);   // A region: a1,a2,a1,a2
    int kw0 = (k0 & 1023) + ((k0 >> 11) << 10);         // W region: w1,w1,w2,w2

    const short* srows[4];
    int lof[4];
    #pragma unroll
    for (int i = 0; i < 4; ++i) {
        int slot = i * 256 + tid;
        int row = slot >> 3;
        int kb  = (slot & 7) * 16;
        const short* g = (row < 64)
            ? (Asrc + (size_t)row * 2048 + ka0)
            : (Wsrc + (size_t)(wc0 + row - 64) * 2048 + kw0);
        srows[i] = g + (kb >> 1);
        lof[i] = row * 128 + (kb ^ ((row & 7) << 4));
    }

    int a_off[4][2], b_off[2];
    #pragma unroll
    for (int m = 0; m < 4; ++m)
        #pragma unroll
        for (int kf = 0; kf < 2; ++kf) {
            int row = m * 16 + (l & 15);
            int kb = kf * 64 + (l >> 4) * 16;
            a_off[m][kf] = row * 128 + (kb ^ ((row & 7) << 4));
        }
    #pragma unroll
    for (int kf = 0; kf < 2; ++kf) {
        int row = 64 + wv * 16 + (l & 15);
        int kb = kf * 64 + (l >> 4) * 16;
        b_off[kf] = row * 128 + (kb ^ ((row & 7) << 4));
    }

    float4 rg[4];
    #pragma unroll
    for (int i = 0; i < 4; ++i) rg[i] = *(const float4*)(srows[i]);

    f32x4 acc[4] = {};

    int cur = 0;
    #pragma unroll 1
    for (int kt = 0; kt < NKT; ++kt) {
        char* buf = tile[cur];
        #pragma unroll
        for (int i = 0; i < 4; ++i) *(float4*)(buf + lof[i]) = rg[i];
        __syncthreads();
        if (kt < NKT - 1) {
            #pragma unroll
            for (int i = 0; i < 4; ++i)
                rg[i] = *(const float4*)(srows[i] + (size_t)(kt + 1) * 64);
        }
        #pragma unroll
        for (int kf = 0; kf < 2; ++kf) {
            bf16x8 bfrag = *(const bf16x8*)(buf + b_off[kf]);
            #pragma unroll
            for (int m = 0; m < 4; ++m) {
                bf16x8 afrag = *(const bf16x8*)(buf + a_off[m][kf]);
                acc[m] = __builtin_amdgcn_mfma_f32_16x16x32_bf16(afrag, bfrag, acc[m], 0, 0, 0);
            }
        }
        cur ^= 1;
        __syncthreads();
    }

    int colw = c0 + wv * 16 + (l & 15);
    #pragma unroll
    for (int m = 0; m < 4; ++m)
        #pragma unroll
        for (int j = 0; j < 4; ++j) {
            int row = m * 16 + (l >> 4) * 4 + j;
            gpart[(size_t)(ks * NB + row) * NC6 + colw] = acc[m][j];
        }
}

// ============ GRU fuse: h = (1-z)*n + z*h (writes ht4 only) ============
__global__ __launch_bounds__(256) void gru_fuse(
    const float* __restrict__ gpart,
    const float* __restrict__ bih, const float* __restrict__ bhh,
    float4* __restrict__ ht4)
{
    int b = blockIdx.x;
    int kg = threadIdx.x;
    int j0 = kg * 4;
    float4 ir = {}, iz = {}, in_ = {}, hr = {}, hz = {}, hn = {};
    #pragma unroll
    for (int ks = 0; ks < 4; ++ks) {
        const float* g = gpart + (size_t)(ks * NB + b) * NC6;
        float4 a;
        a = *(const float4*)&g[j0];             ir.x+=a.x; ir.y+=a.y; ir.z+=a.z; ir.w+=a.w;
        a = *(const float4*)&g[HD + j0];        iz.x+=a.x; iz.y+=a.y; iz.z+=a.z; iz.w+=a.w;
        a = *(const float4*)&g[2*HD + j0];      in_.x+=a.x; in_.y+=a.y; in_.z+=a.z; in_.w+=a.w;
        a = *(const float4*)&g[H3 + j0];        hr.x+=a.x; hr.y+=a.y; hr.z+=a.z; hr.w+=a.w;
        a = *(const float4*)&g[H3 + HD + j0];   hz.x+=a.x; hz.y+=a.y; hz.z+=a.z; hz.w+=a.w;
        a = *(const float4*)&g[H3 + 2*HD + j0]; hn.x+=a.x; hn.y+=a.y; hn.z+=a.z; hn.w+=a.w;
    }
    float4 vbi0 = *(const float4*)&bih[j0];
    float4 vbi1 = *(const float4*)&bih[HD + j0];
    float4 vbi2 = *(const float4*)&bih[2*HD + j0];
    float4 vbh0 = *(const float4*)&bhh[j0];
    float4 vbh1 = *(const float4*)&bhh[HD + j0];
    float4 vbh2 = *(const float4*)&bhh[2*HD + j0];
    float4 hv = ht4[kg * NB + b];
    float irv[4] = {ir.x+vbi0.x, ir.y+vbi0.y, ir.z+vbi0.z, ir.w+vbi0.w};
    float izv[4] = {iz.x+vbi1.x, iz.y+vbi1.y, iz.z+vbi1.z, iz.w+vbi1.w};
    float inv[4] = {in_.x+vbi2.x, in_.y+vbi2.y, in_.z+vbi2.z, in_.w+vbi2.w};
    float hrv[4] = {hr.x+vbh0.x, hr.y+vbh0.y, hr.z+vbh0.z, hr.w+vbh0.w};
    float hzv[4] = {hz.x+vbh1.x, hz.y+vbh1.y, hz.z+vbh1.z, hz.w+vbh1.w};
    float hnv[4] = {hn.x+vbh2.x, hn.y+vbh2.y, hn.z+vbh2.z, hn.w+vbh2.w};
    float hvv[4] = {hv.x, hv.y, hv.z, hv.w};
    float o[4];
    #pragma unroll
    for (int u = 0; u < 4; ++u) {
        float r = sigmoidf_(irv[u] + hrv[u]);
        float z = sigmoidf_(izv[u] + hzv[u]);
        float n = tanhf(inv[u] + r * hnv[u]);
        o[u] = (1.0f - z) * n + z * hvv[u];
    }
    ht4[kg * NB + b] = make_float4(o[0], o[1], o[2], o[3]);
}

// ============ per-step: ht4 -> Hsp (2-way split) + hnorm ============
__global__ __launch_bounds__(256) void hsplit_kernel(const float4* __restrict__ ht4,
                                                     short* __restrict__ Hsp,
                                                     float* __restrict__ hnorm)
{
    int b = blockIdx.x, kg = threadIdx.x;
    float4 v = ht4[kg * NB + b];
    float xs[4] = {v.x, v.y, v.z, v.w};
    s16x4 p1, p2;
    #pragma unroll
    for (int e = 0; e < 4; ++e) {
        short s1 = bf16bits(xs[e]);
        short s2 = bf16bits(xs[e] - bf16val(s1));
        p1[e] = s1; p2[e] = s2;
    }
    *(s16x4*)(Hsp + (size_t)b * 2048 + kg * 4)        = p1;
    *(s16x4*)(Hsp + (size_t)b * 2048 + 1024 + kg * 4) = p2;
    float ss = xs[0]*xs[0] + xs[1]*xs[1] + xs[2]*xs[2] + xs[3]*xs[3];
    #pragma unroll
    for (int off = 32; off; off >>= 1) ss += __shfl_xor(ss, off);
    __shared__ float red[4];
    if ((kg & 63) == 0) red[kg >> 6] = ss;
    __syncthreads();
    if (kg == 0) hnorm[b] = sqrtf(red[0] + red[1] + red[2] + red[3]);
}

// ============ logits screen: bf16 MFMA -> lb + per-block lower-bound max ============
__global__ __launch_bounds__(256, 2) void logits_lb(
    const short* __restrict__ Hsp, const short* __restrict__ Wbf,
    const float* __restrict__ bout, const float* __restrict__ wnorm,
    const float* __restrict__ hnorm,
    float* __restrict__ lb, float* __restrict__ bmlow)
{
    __shared__ __align__(16) char tile[2][16384];
    __shared__ float smax[64][4];

    const int tid = threadIdx.x;
    const int wv = tid >> 6, l = tid & 63;
    const int blk = blockIdx.x;

    const short* srows[4];
    int lof[4];
    #pragma unroll
    for (int i = 0; i < 4; ++i) {
        int slot = i * 256 + tid;
        int row = slot >> 3;
        int kb  = (slot & 7) * 16;
        const short* g = (row < 64)
            ? (Hsp + (size_t)row * 2048)                      // h1 half
            : (Wbf + ((size_t)(blk * 64 + (row - 64))) * HD);
        srows[i] = g + (kb >> 1);
        lof[i] = row * 128 + (kb ^ ((row & 7) << 4));
    }

    int a_off[4][2], b_off[2];
    #pragma unroll
    for (int m = 0; m < 4; ++m)
        #pragma unroll
        for (int kf = 0; kf < 2; ++kf) {
            int row = m * 16 + (l & 15);
            int kb = kf * 64 + (l >> 4) * 16;
            a_off[m][kf] = row * 128 + (kb ^ ((row & 7) << 4));
        }
    #pragma unroll
    for (int kf = 0; kf < 2; ++kf) {
        int row = 64 + wv * 16 + (l & 15);
        int kb = kf * 64 + (l >> 4) * 16;
        b_off[kf] = row * 128 + (kb ^ ((row & 7) << 4));
    }

    float4 rg[4];
    #pragma unroll
    for (int i = 0; i < 4; ++i) rg[i] = *(const float4*)(srows[i]);

    f32x4 acc[4] = {};

    int cur = 0;
    #pragma unroll 1
    for (int kt = 0; kt < NKT; ++kt) {
        char* buf = tile[cur];
        #pragma unroll
        for (int i = 0; i < 4; ++i) *(float4*)(buf + lof[i]) = rg[i];
        __syncthreads();
        if (kt < NKT - 1) {
            #pragma unroll
            for (int i = 0; i < 4; ++i)
                rg[i] = *(const float4*)(srows[i] + (size_t)(kt + 1) * 64);
        }
        #pragma unroll
        for (int kf = 0; kf < 2; ++kf) {
            bf16x8 bfrag = *(const bf16x8*)(buf + b_off[kf]);
            #pragma unroll
            for (int m = 0; m < 4; ++m) {
                bf16x8 afrag = *(const bf16x8*)(buf + a_off[m][kf]);
                acc[m] = __builtin_amdgcn_mfma_f32_16x16x32_bf16(afrag, bfrag, acc[m], 0, 0, 0);
            }
        }
        cur ^= 1;
        __syncthreads();
    }

    int col = blk * 64 + wv * 16 + (l & 15);
    float bo = bout[col];
    float wn = wnorm[col];
    float selmax = -FLT_MAX;
    int pick = l & 15;
    #pragma unroll
    for (int m = 0; m < 4; ++m) {
        #pragma unroll
        for (int j = 0; j < 4; ++j) {
            int row = m * 16 + (l >> 4) * 4 + j;
            float lbv = acc[m][j] + bo;
            lb[(size_t)row * NV + col] = lbv;
            float low = lbv - (MARGIN_COEF * hnorm[row] * wn + MARGIN_ABS);
            #pragma unroll
            for (int mask = 1; mask <= 8; mask <<= 1)
                low = fmaxf(low, __shfl_xor(low, mask, 64));
            if (pick == m * 4 + j) selmax = low;
        }
    }
    int row = ((l & 15) >> 2) * 16 + (l >> 4) * 4 + (l & 3);
    smax[row][wv] = selmax;
    __syncthreads();
    if (wv == 0) {
        float v = fmaxf(fmaxf(smax[l][0], smax[l][1]), fmaxf(smax[l][2], smax[l][3]));
        bmlow[(size_t)l * BML + blk] = v;
    }
}

// ============ T[b] = max over blocks of bmlow; reset best ============
__global__ __launch_bounds__(512) void tmax_kernel(const float* __restrict__ bmlow,
                                                   float* __restrict__ T,
                                                   unsigned long long* __restrict__ best)
{
    int b = blockIdx.x, tid = threadIdx.x;
    float v = (tid < LBLK) ? bmlow[(size_t)b * BML + tid] : -FLT_MAX;
    #pragma unroll
    for (int off = 32; off; off >>= 1) v = fmaxf(v, __shfl_xor(v, off));
    __shared__ float red[8];
    if ((tid & 63) == 0) red[tid >> 6] = v;
    __syncthreads();
    if (tid == 0) {
        float m = red[0];
        #pragma unroll
        for (int w = 1; w < 8; ++w) m = fmaxf(m, red[w]);
        T[b] = m;
        best[b] = 0ull;
    }
}

// ============ select candidates + exact fp32 rescore + atomic commit ============
// grid 64*NSLICE: b = blk>>3, slice = blk&7 (4000 cols each). 256 thr.
__global__ __launch_bounds__(256) void select2_kernel(
    const float* __restrict__ lb, const float* __restrict__ wnorm,
    const float* __restrict__ hnorm, const float* __restrict__ T,
    const float* __restrict__ Wout, const float* __restrict__ bout,
    const float4* __restrict__ ht4,
    unsigned long long* __restrict__ best)
{
    int b = blockIdx.x >> 3, slice = blockIdx.x & 7;
    int tid = threadIdx.x, wv = tid >> 6;
    const float* lbr = lb + (size_t)b * NV;
    float coef = MARGIN_COEF * hnorm[b];
    float tb = T[b];

    __shared__ int scount;
    __shared__ int cand[MAXCAND];
    if (tid == 0) scount = 0;
    __syncthreads();

    int c0 = slice * (NV / NSLICE);
    for (int c = c0 + tid; c < c0 + NV / NSLICE; c += 256) {
        if (lbr[c] + (coef * wnorm[c] + MARGIN_ABS) >= tb) {
            int s = atomicAdd(&scount, 1);
            if (s < MAXCAND) cand[s] = c;
        }
    }
    __syncthreads();
    int n = scount < MAXCAND ? scount : MAXCAND;
    if (n == 0) return;

    float4 h4 = ht4[tid * NB + b];
    __shared__ float rsum[4];
    for (int s = 0; s < n; ++s) {
        int c = cand[s];
        float4 w4 = *(const float4*)&Wout[(size_t)c * HD + tid * 4];
        float p = dot4(h4, w4, 0.0f);
        #pragma unroll
        for (int off = 32; off; off >>= 1) p += __shfl_xor(p, off);
        if ((tid & 63) == 0) rsum[wv] = p;
        __syncthreads();
        if (tid == 0) {
            float tot = rsum[0] + rsum[1] + rsum[2] + rsum[3] + bout[c];
            unsigned long long key =
                ((unsigned long long)ordbits(tot) << 32) | (unsigned)(~c);
            atomicMax(&best[b], key);
        }
        __syncthreads();
    }
}

// ============ gather winner: resps + Xsp (split emb row) ============
__global__ __launch_bounds__(256) void gather_kernel(
    const unsigned long long* __restrict__ best,
    const float* __restrict__ emb, int* __restrict__ resps, int t,
    short* __restrict__ Xsp)
{
    int b = blockIdx.x, tid = threadIdx.x;
    int c = ~(unsigned)(best[b] & 0xFFFFFFFFull);
    if (tid == 0) resps[b * TSTEPS + t] = c;
    int k = tid * 4;
    float4 e = *(const float4*)&emb[(size_t)c * HD + k];
    float xs[4] = {e.x, e.y, e.z, e.w};
    s16x4 p1, p2;
    #pragma unroll
    for (int u = 0; u < 4; ++u) {
        short s1 = bf16bits(xs[u]);
        short s2 = bf16bits(xs[u] - bf16val(s1));
        p1[u] = s1; p2[u] = s2;
    }
    *(s16x4*)(Xsp + (size_t)b * 2048 + k)        = p1;
    *(s16x4*)(Xsp + (size_t)b * 2048 + 1024 + k) = p2;
}

// ---------------- resp_lens ----------------
__global__ void resp_lens_kernel(const int* __restrict__ resps, int* __restrict__ lens)
{
    int b = threadIdx.x;
    if (b >= NB) return;
    int len = TSTEPS + 1;
    for (int t = TSTEPS - 1; t >= 0; t--)
        if (resps[b * TSTEPS + t] == 2) len = t + 1;
    lens[b] = len;
}

extern "C" void kernel_launch(void* const* d_in, const int* in_sizes, int n_in,
                              void* d_out, int out_size, void* d_ws, size_t ws_size,
                              hipStream_t stream) {
    const float* zs   = (const float*)d_in[0];
    const float* cs   = (const float*)d_in[1];
    const float* emb  = (const float*)d_in[2];
    const float* Wih  = (const float*)d_in[3];
    const float* Whh  = (const float*)d_in[4];
    const float* bih  = (const float*)d_in[5];
    const float* bhh  = (const float*)d_in[6];
    const float* Wout = (const float*)d_in[7];
    const float* bout = (const float*)d_in[8];
    int* out = (int*)d_out;  // [64*32 resps][64 lens], int32

    char* ws = (char*)d_ws;
    float4* ht4  = (float4*)ws; ws += (size_t)256 * NB * 16;          // 256 KB
    float*  gpart = (float*)ws; ws += (size_t)4 * NB * NC6 * 4;       // 6.3 MB
    short*  Hsp  = (short*)ws;  ws += (size_t)NB * 2048 * 2;          // 256 KB
    short*  Xsp  = (short*)ws;  ws += (size_t)NB * 2048 * 2;          // 256 KB
    float*  wnorm = (float*)ws; ws += (size_t)NV * 4;                 // 128 KB
    float*  hnorm = (float*)ws; ws += 256;
    float*  bmlow = (float*)ws; ws += (size_t)NB * BML * 4;           // 128 KB
    float*  Tb   = (float*)ws;  ws += 256;
    unsigned long long* best = (unsigned long long*)ws; ws += NB * 8;
    float*  lb   = (float*)ws;  ws += (size_t)NB * NV * 4;            // 8.2 MB
    short*  Wbf  = (short*)ws;  ws += (size_t)NV * HD * 2;            // 65.5 MB
    short*  WihSp = (short*)ws; ws += (size_t)H3 * 2048 * 2;          // 12.6 MB
    short*  WhhSp = (short*)ws; ws += (size_t)H3 * 2048 * 2;          // 12.6 MB

    wsplit2_kernel<<<NC6, 256, 0, stream>>>(Wih, Whh, WihSp, WhhSp);
    wbf_kernel<<<NV, 256, 0, stream>>>(Wout, Wbf, wnorm);
    init_kernel<<<NB, 256, 0, stream>>>(zs, cs, emb, ht4, Hsp, Xsp, hnorm);
    for (int t = 0; t < TSTEPS; t++) {
        gates_mfma<<<96 * 4, 256, 0, stream>>>(Xsp, Hsp, WihSp, WhhSp, gpart);
        gru_fuse<<<NB, 256, 0, stream>>>(gpart, bih, bhh, ht4);
        hsplit_kernel<<<NB, 256, 0, stream>>>(ht4, Hsp, hnorm);
        logits_lb<<<LBLK, 256, 0, stream>>>(Hsp, Wbf, bout, wnorm, hnorm, lb, bmlow);
        tmax_kernel<<<NB, 512, 0, stream>>>(bmlow, Tb, best);
        select2_kernel<<<NB * NSLICE, 256, 0, stream>>>(lb, wnorm, hnorm, Tb,
                                                        Wout, bout, ht4, best);
        gather_kernel<<<NB, 256, 0, stream>>>(best, emb, out, t, Xsp);
    }
    resp_lens_kernel<<<1, 64, 0, stream>>>(out, out + NB * TSTEPS);
}

// Round 15
// 1596.897 us; speedup vs baseline: 3.0637x; 2.0932x over previous
//
#include <hip/hip_runtime.h>
#include <hip/hip_bf16.h>
#include <float.h>

#define NB 64
#define HD 1024
#define H3 3072
#define NC6 6144
#define NV 32000
#define TSTEPS 32
#define LBLK 500        // logits blocks (64 cols each)
#define BML 512         // bmlow stride (>= LBLK)
#define NSLICE 8        // select2 col slices
#define NKT 16          // 16 K-steps of 64 per GEMM kernel
#define MARGIN_COEF 0.010f
#define MARGIN_ABS  1e-3f
#define MAXCAND 1024

using bf16x8 = __attribute__((ext_vector_type(8))) short;
using f32x4  = __attribute__((ext_vector_type(4))) float;
using s16x4  = __attribute__((ext_vector_type(4))) short;

// pre-swizzle: XOR 16-B blocks within each 128-B segment by (row&7)<<4.
// Writers store logical (row, bo) at SWZ(row,bo); linear LDS-DMA then yields the
// exact layout the MFMA fragment ds_reads (which XOR the same bits) expect.
#define SWZ(row, bo) ((((bo) & ~127)) | (((bo) & 112) ^ (((row) & 7) << 4)) | ((bo) & 15))

__device__ __forceinline__ void gl_lds16(const void* g, void* l) {
    __builtin_amdgcn_global_load_lds(
        (const __attribute__((address_space(1))) void*)g,
        (__attribute__((address_space(3))) void*)l, 16, 0, 0);
}
__device__ __forceinline__ float sigmoidf_(float x) {
    return 1.0f / (1.0f + expf(-x));
}
__device__ __forceinline__ float dot4(float4 h, float4 w, float a) {
    return fmaf(h.w, w.w, fmaf(h.z, w.z, fmaf(h.y, w.y, fmaf(h.x, w.x, a))));
}
__device__ __forceinline__ short bf16bits(float x) {
    __hip_bfloat16 b = __float2bfloat16(x);
    return __builtin_bit_cast(short, b);
}
__device__ __forceinline__ float bf16val(short s) {
    __hip_bfloat16 b = __builtin_bit_cast(__hip_bfloat16, s);
    return __bfloat162float(b);
}
__device__ __forceinline__ unsigned ordbits(float v) {
    unsigned u = __float_as_uint(v);
    return (u & 0x80000000u) ? ~u : (u | 0x80000000u);
}

// ============ one-time: Wih/Whh -> 2-way split [row][2048] = [w1|w2], pre-swizzled ============
__global__ __launch_bounds__(256) void wsplit2_kernel(
    const float* __restrict__ Wih, const float* __restrict__ Whh,
    short* __restrict__ WihSp, short* __restrict__ WhhSp)
{
    int r = blockIdx.x;             // 0..6143
    const float* src = (r < H3) ? &Wih[(size_t)r * HD] : &Whh[(size_t)(r - H3) * HD];
    char* dst = (char*)((r < H3) ? &WihSp[(size_t)r * 2048] : &WhhSp[(size_t)(r - H3) * 2048]);
    int k = threadIdx.x * 4;
    float4 v = *(const float4*)&src[k];
    float xs[4] = {v.x, v.y, v.z, v.w};
    s16x4 p1, p2;
    #pragma unroll
    for (int e = 0; e < 4; ++e) {
        short s1 = bf16bits(xs[e]);
        short s2 = bf16bits(xs[e] - bf16val(s1));
        p1[e] = s1; p2[e] = s2;
    }
    int bo = k * 2;                 // byte offset of the 8-B unit
    *(s16x4*)(dst + SWZ(r, bo))        = p1;
    *(s16x4*)(dst + SWZ(r, 2048 + bo)) = p2;
}

// ============ one-time: Wout -> Wbf (bf16, pre-swizzled) + wnorm ============
__global__ __launch_bounds__(256) void wbf_kernel(const float* __restrict__ W,
                                                  short* __restrict__ Wbf,
                                                  float* __restrict__ wnorm)
{
    int r = blockIdx.x, tdx = threadIdx.x;
    float4 v = *(const float4*)&W[(size_t)r * HD + tdx * 4];
    s16x4 p;
    p[0] = bf16bits(v.x); p[1] = bf16bits(v.y);
    p[2] = bf16bits(v.z); p[3] = bf16bits(v.w);
    char* dst = (char*)(Wbf + (size_t)r * HD);
    *(s16x4*)(dst + SWZ(r, tdx * 8)) = p;
    float ss = v.x*v.x + v.y*v.y + v.z*v.z + v.w*v.w;
    #pragma unroll
    for (int off = 32; off; off >>= 1) ss += __shfl_xor(ss, off);
    __shared__ float red[4];
    if ((tdx & 63) == 0) red[tdx >> 6] = ss;
    __syncthreads();
    if (tdx == 0) wnorm[r] = sqrtf(red[0] + red[1] + red[2] + red[3]);
}

// ============ init: ht4 + Hsp + Xsp (pre-swizzled) + hnorm + best reset ============
__global__ __launch_bounds__(256) void init_kernel(
    const float* __restrict__ zs, const float* __restrict__ cs,
    const float* __restrict__ emb,
    float4* __restrict__ ht4, short* __restrict__ Hsp, short* __restrict__ Xsp,
    float* __restrict__ hnorm, unsigned long long* __restrict__ best)
{
    int b = blockIdx.x;
    int kg = threadIdx.x;
    int j = kg * 4;
    float4 v;
    if (j < 512) v = *(const float4*)&zs[b * 512 + j];
    else         v = *(const float4*)&cs[b * 512 + (j - 512)];
    ht4[kg * NB + b] = v;
    float hs[4] = {v.x, v.y, v.z, v.w};
    s16x4 p1, p2;
    #pragma unroll
    for (int e = 0; e < 4; ++e) {
        short s1 = bf16bits(hs[e]);
        short s2 = bf16bits(hs[e] - bf16val(s1));
        p1[e] = s1; p2[e] = s2;
    }
    int bo = j * 2;
    char* hdst = (char*)(Hsp + (size_t)b * 2048);
    *(s16x4*)(hdst + SWZ(b, bo))        = p1;
    *(s16x4*)(hdst + SWZ(b, 2048 + bo)) = p2;

    float4 x = *(const float4*)&emb[HD + j];  // SOS = 1
    float xs[4] = {x.x, x.y, x.z, x.w};
    #pragma unroll
    for (int e = 0; e < 4; ++e) {
        short s1 = bf16bits(xs[e]);
        short s2 = bf16bits(xs[e] - bf16val(s1));
        p1[e] = s1; p2[e] = s2;
    }
    char* xdst = (char*)(Xsp + (size_t)b * 2048);
    *(s16x4*)(xdst + SWZ(b, bo))        = p1;
    *(s16x4*)(xdst + SWZ(b, 2048 + bo)) = p2;

    float ss = hs[0]*hs[0] + hs[1]*hs[1] + hs[2]*hs[2] + hs[3]*hs[3];
    #pragma unroll
    for (int off = 32; off; off >>= 1) ss += __shfl_xor(ss, off);
    __shared__ float red[4];
    if ((kg & 63) == 0) red[kg >> 6] = ss;
    __syncthreads();
    if (kg == 0) {
        hnorm[b] = sqrtf(red[0] + red[1] + red[2] + red[3]);
        best[b] = 0ull;
    }
}

// ============ gates: 2-way-split full-product MFMA, K-split 4, gload_lds staging ============
// grid 384: cg = blk>>2 (64 cols of 6144), ks = blk&3 (k'' slice of 1024).
// K''=4096 arranged A'=[a1|a2|a1|a2], W'=[w1|w1|w2|w2] -> all 4 cross terms.
__global__ __launch_bounds__(256, 2) void gates_mfma(
    const short* __restrict__ Xsp, const short* __restrict__ Hsp,
    const short* __restrict__ WihSp, const short* __restrict__ WhhSp,
    float* __restrict__ gpart)
{
    __shared__ __align__(16) char tile[2][16384];

    const int tid = threadIdx.x;
    const int wv = tid >> 6, l = tid & 63;
    int cg = blockIdx.x >> 2;
    int ks = blockIdx.x & 3;
    int c0 = cg * 64;
    bool isH = c0 >= H3;
    const short* __restrict__ Asrc = isH ? Hsp : Xsp;
    const short* __restrict__ Wsrc = isH ? WhhSp : WihSp;
    int wc0 = c0 - (isH ? H3 : 0);
    int k0 = ks * 1024;
    int ka0 = (k0 & 1023) + (((k0 >> 10) & 1) << 10);   // A region: a1,a2,a1,a2
    int kw0 = (k0 & 1023) + ((k0 >> 11) << 10);         // W region: w1,w1,w2,w2

    // staging: slot = i*256+tid -> LDS linear slot*16; global pre-swizzled linear
    const short* srows[4];
    int lof[4];
    #pragma unroll
    for (int i = 0; i < 4; ++i) {
        int slot = i * 256 + tid;
        int row = slot >> 3;
        int kb  = (slot & 7) * 16;
        const short* g = (row < 64)
            ? (Asrc + (size_t)row * 2048 + ka0)
            : (Wsrc + (size_t)(wc0 + row - 64) * 2048 + kw0);
        srows[i] = g + (kb >> 1);
        lof[i] = slot * 16;
    }

    int a_off[4][2], b_off[2];
    #pragma unroll
    for (int m = 0; m < 4; ++m)
        #pragma unroll
        for (int kf = 0; kf < 2; ++kf) {
            int row = m * 16 + (l & 15);
            int kb = kf * 64 + (l >> 4) * 16;
            a_off[m][kf] = row * 128 + (kb ^ ((row & 7) << 4));
        }
    #pragma unroll
    for (int kf = 0; kf < 2; ++kf) {
        int row = 64 + wv * 16 + (l & 15);
        int kb = kf * 64 + (l >> 4) * 16;
        b_off[kf] = row * 128 + (kb ^ ((row & 7) << 4));
    }

    f32x4 acc[4] = {};

    #pragma unroll
    for (int i = 0; i < 4; ++i) gl_lds16(srows[i], tile[0] + lof[i]);
    __syncthreads();

    int cur = 0;
    #pragma unroll 1
    for (int kt = 0; kt < NKT; ++kt) {
        if (kt + 1 < NKT) {
            #pragma unroll
            for (int i = 0; i < 4; ++i)
                gl_lds16(srows[i] + (size_t)(kt + 1) * 64, tile[cur ^ 1] + lof[i]);
        }
        char* buf = tile[cur];
        #pragma unroll
        for (int kf = 0; kf < 2; ++kf) {
            bf16x8 bfrag = *(const bf16x8*)(buf + b_off[kf]);
            #pragma unroll
            for (int m = 0; m < 4; ++m) {
                bf16x8 afrag = *(const bf16x8*)(buf + a_off[m][kf]);
                acc[m] = __builtin_amdgcn_mfma_f32_16x16x32_bf16(afrag, bfrag, acc[m], 0, 0, 0);
            }
        }
        __syncthreads();
        cur ^= 1;
    }

    int colw = c0 + wv * 16 + (l & 15);
    #pragma unroll
    for (int m = 0; m < 4; ++m)
        #pragma unroll
        for (int j = 0; j < 4; ++j) {
            int row = m * 16 + (l >> 4) * 4 + j;
            gpart[(size_t)(ks * NB + row) * NC6 + colw] = acc[m][j];
        }
}

// ============ GRU fuse + hsplit epilogue (pre-swizzled Hsp) + hnorm + best reset ============
__global__ __launch_bounds__(256) void gru_fuse(
    const float* __restrict__ gpart,
    const float* __restrict__ bih, const float* __restrict__ bhh,
    float4* __restrict__ ht4, short* __restrict__ Hsp,
    float* __restrict__ hnorm, unsigned long long* __restrict__ best)
{
    int b = blockIdx.x;
    int kg = threadIdx.x;
    int j0 = kg * 4;
    float4 ir = {}, iz = {}, in_ = {}, hr = {}, hz = {}, hn = {};
    #pragma unroll
    for (int ks = 0; ks < 4; ++ks) {
        const float* g = gpart + (size_t)(ks * NB + b) * NC6;
        float4 a;
        a = *(const float4*)&g[j0];             ir.x+=a.x; ir.y+=a.y; ir.z+=a.z; ir.w+=a.w;
        a = *(const float4*)&g[HD + j0];        iz.x+=a.x; iz.y+=a.y; iz.z+=a.z; iz.w+=a.w;
        a = *(const float4*)&g[2*HD + j0];      in_.x+=a.x; in_.y+=a.y; in_.z+=a.z; in_.w+=a.w;
        a = *(const float4*)&g[H3 + j0];        hr.x+=a.x; hr.y+=a.y; hr.z+=a.z; hr.w+=a.w;
        a = *(const float4*)&g[H3 + HD + j0];   hz.x+=a.x; hz.y+=a.y; hz.z+=a.z; hz.w+=a.w;
        a = *(const float4*)&g[H3 + 2*HD + j0]; hn.x+=a.x; hn.y+=a.y; hn.z+=a.z; hn.w+=a.w;
    }
    float4 vbi0 = *(const float4*)&bih[j0];
    float4 vbi1 = *(const float4*)&bih[HD + j0];
    float4 vbi2 = *(const float4*)&bih[2*HD + j0];
    float4 vbh0 = *(const float4*)&bhh[j0];
    float4 vbh1 = *(const float4*)&bhh[HD + j0];
    float4 vbh2 = *(const float4*)&bhh[2*HD + j0];
    float4 hv = ht4[kg * NB + b];
    float irv[4] = {ir.x+vbi0.x, ir.y+vbi0.y, ir.z+vbi0.z, ir.w+vbi0.w};
    float izv[4] = {iz.x+vbi1.x, iz.y+vbi1.y, iz.z+vbi1.z, iz.w+vbi1.w};
    float inv[4] = {in_.x+vbi2.x, in_.y+vbi2.y, in_.z+vbi2.z, in_.w+vbi2.w};
    float hrv[4] = {hr.x+vbh0.x, hr.y+vbh0.y, hr.z+vbh0.z, hr.w+vbh0.w};
    float hzv[4] = {hz.x+vbh1.x, hz.y+vbh1.y, hz.z+vbh1.z, hz.w+vbh1.w};
    float hnv[4] = {hn.x+vbh2.x, hn.y+vbh2.y, hn.z+vbh2.z, hn.w+vbh2.w};
    float hvv[4] = {hv.x, hv.y, hv.z, hv.w};
    float o[4];
    #pragma unroll
    for (int u = 0; u < 4; ++u) {
        float r = sigmoidf_(irv[u] + hrv[u]);
        float z = sigmoidf_(izv[u] + hzv[u]);
        float n = tanhf(inv[u] + r * hnv[u]);
        o[u] = (1.0f - z) * n + z * hvv[u];
    }
    ht4[kg * NB + b] = make_float4(o[0], o[1], o[2], o[3]);

    s16x4 p1, p2;
    #pragma unroll
    for (int e = 0; e < 4; ++e) {
        short s1 = bf16bits(o[e]);
        short s2 = bf16bits(o[e] - bf16val(s1));
        p1[e] = s1; p2[e] = s2;
    }
    int bo = j0 * 2;
    char* hdst = (char*)(Hsp + (size_t)b * 2048);
    *(s16x4*)(hdst + SWZ(b, bo))        = p1;
    *(s16x4*)(hdst + SWZ(b, 2048 + bo)) = p2;

    float ss = o[0]*o[0] + o[1]*o[1] + o[2]*o[2] + o[3]*o[3];
    #pragma unroll
    for (int off = 32; off; off >>= 1) ss += __shfl_xor(ss, off);
    __shared__ float red[4];
    if ((kg & 63) == 0) red[kg >> 6] = ss;
    __syncthreads();
    if (kg == 0) {
        hnorm[b] = sqrtf(red[0] + red[1] + red[2] + red[3]);
        best[b] = 0ull;
    }
}

// ============ logits screen: bf16 MFMA (gload_lds) -> lb + per-block lower-bound max ============
__global__ __launch_bounds__(256, 2) void logits_lb(
    const short* __restrict__ Hsp, const short* __restrict__ Wbf,
    const float* __restrict__ bout, const float* __restrict__ wnorm,
    const float* __restrict__ hnorm,
    float* __restrict__ lb, float* __restrict__ bmlow)
{
    __shared__ __align__(16) char tile[2][16384];
    __shared__ float smax[64][4];

    const int tid = threadIdx.x;
    const int wv = tid >> 6, l = tid & 63;
    const int blk = blockIdx.x;

    const short* srows[4];
    int lof[4];
    #pragma unroll
    for (int i = 0; i < 4; ++i) {
        int slot = i * 256 + tid;
        int row = slot >> 3;
        int kb  = (slot & 7) * 16;
        const short* g = (row < 64)
            ? (Hsp + (size_t)row * 2048)                      // h1 half (first 1024)
            : (Wbf + ((size_t)(blk * 64 + (row - 64))) * HD);
        srows[i] = g + (kb >> 1);
        lof[i] = slot * 16;
    }

    int a_off[4][2], b_off[2];
    #pragma unroll
    for (int m = 0; m < 4; ++m)
        #pragma unroll
        for (int kf = 0; kf < 2; ++kf) {
            int row = m * 16 + (l & 15);
            int kb = kf * 64 + (l >> 4) * 16;
            a_off[m][kf] = row * 128 + (kb ^ ((row & 7) << 4));
        }
    #pragma unroll
    for (int kf = 0; kf < 2; ++kf) {
        int row = 64 + wv * 16 + (l & 15);
        int kb = kf * 64 + (l >> 4) * 16;
        b_off[kf] = row * 128 + (kb ^ ((row & 7) << 4));
    }

    f32x4 acc[4] = {};

    #pragma unroll
    for (int i = 0; i < 4; ++i) gl_lds16(srows[i], tile[0] + lof[i]);
    __syncthreads();

    int cur = 0;
    #pragma unroll 1
    for (int kt = 0; kt < NKT; ++kt) {
        if (kt + 1 < NKT) {
            #pragma unroll
            for (int i = 0; i < 4; ++i)
                gl_lds16(srows[i] + (size_t)(kt + 1) * 64, tile[cur ^ 1] + lof[i]);
        }
        char* buf = tile[cur];
        #pragma unroll
        for (int kf = 0; kf < 2; ++kf) {
            bf16x8 bfrag = *(const bf16x8*)(buf + b_off[kf]);
            #pragma unroll
            for (int m = 0; m < 4; ++m) {
                bf16x8 afrag = *(const bf16x8*)(buf + a_off[m][kf]);
                acc[m] = __builtin_amdgcn_mfma_f32_16x16x32_bf16(afrag, bfrag, acc[m], 0, 0, 0);
            }
        }
        __syncthreads();
        cur ^= 1;
    }

    int col = blk * 64 + wv * 16 + (l & 15);
    float bo = bout[col];
    float wn = wnorm[col];
    float selmax = -FLT_MAX;
    int pick = l & 15;
    #pragma unroll
    for (int m = 0; m < 4; ++m) {
        #pragma unroll
        for (int j = 0; j < 4; ++j) {
            int row = m * 16 + (l >> 4) * 4 + j;
            float lbv = acc[m][j] + bo;
            lb[(size_t)row * NV + col] = lbv;
            float low = lbv - (MARGIN_COEF * hnorm[row] * wn + MARGIN_ABS);
            #pragma unroll
            for (int mask = 1; mask <= 8; mask <<= 1)
                low = fmaxf(low, __shfl_xor(low, mask, 64));
            if (pick == m * 4 + j) selmax = low;
        }
    }
    int row = ((l & 15) >> 2) * 16 + (l >> 4) * 4 + (l & 3);
    smax[row][wv] = selmax;
    __syncthreads();
    if (wv == 0) {
        float v = fmaxf(fmaxf(smax[l][0], smax[l][1]), fmaxf(smax[l][2], smax[l][3]));
        bmlow[(size_t)l * BML + blk] = v;
    }
}

// ============ select: inline T reduce + candidates + exact fp32 rescore + commit ============
// grid 64*NSLICE: b = blk>>3, slice = blk&7 (4000 cols each). 256 thr.
__global__ __launch_bounds__(256) void select2_kernel(
    const float* __restrict__ lb, const float* __restrict__ wnorm,
    const float* __restrict__ hnorm, const float* __restrict__ bmlow,
    const float* __restrict__ Wout, const float* __restrict__ bout,
    const float4* __restrict__ ht4,
    unsigned long long* __restrict__ best)
{
    int b = blockIdx.x >> 3, slice = blockIdx.x & 7;
    int tid = threadIdx.x, wv = tid >> 6;
    const float* lbr = lb + (size_t)b * NV;
    float coef = MARGIN_COEF * hnorm[b];

    __shared__ int scount;
    __shared__ int cand[MAXCAND];
    __shared__ float tred[4];
    if (tid == 0) scount = 0;

    // inline T[b]: reduce bmlow row (2 KB, deterministic, no atomics)
    float tv = -FLT_MAX;
    for (int i = tid; i < LBLK; i += 256) tv = fmaxf(tv, bmlow[(size_t)b * BML + i]);
    #pragma unroll
    for (int off = 32; off; off >>= 1) tv = fmaxf(tv, __shfl_xor(tv, off));
    if ((tid & 63) == 0) tred[wv] = tv;
    __syncthreads();
    float tb = fmaxf(fmaxf(tred[0], tred[1]), fmaxf(tred[2], tred[3]));

    int c0 = slice * (NV / NSLICE);
    for (int c = c0 + tid; c < c0 + NV / NSLICE; c += 256) {
        if (lbr[c] + (coef * wnorm[c] + MARGIN_ABS) >= tb) {
            int s = atomicAdd(&scount, 1);
            if (s < MAXCAND) cand[s] = c;
        }
    }
    __syncthreads();
    int n = scount < MAXCAND ? scount : MAXCAND;
    if (n == 0) return;

    float4 h4 = ht4[tid * NB + b];
    __shared__ float rsum[4];
    for (int s = 0; s < n; ++s) {
        int c = cand[s];
        float4 w4 = *(const float4*)&Wout[(size_t)c * HD + tid * 4];
        float p = dot4(h4, w4, 0.0f);
        #pragma unroll
        for (int off = 32; off; off >>= 1) p += __shfl_xor(p, off);
        if ((tid & 63) == 0) rsum[wv] = p;
        __syncthreads();
        if (tid == 0) {
            float tot = rsum[0] + rsum[1] + rsum[2] + rsum[3] + bout[c];
            unsigned long long key =
                ((unsigned long long)ordbits(tot) << 32) | (unsigned)(~c);
            atomicMax(&best[b], key);
        }
        __syncthreads();
    }
}

// ============ gather winner: resps + Xsp (pre-swizzled split emb row) ============
__global__ __launch_bounds__(256) void gather_kernel(
    const unsigned long long* __restrict__ best,
    const float* __restrict__ emb, int* __restrict__ resps, int t,
    short* __restrict__ Xsp)
{
    int b = blockIdx.x, tid = threadIdx.x;
    int c = ~(unsigned)(best[b] & 0xFFFFFFFFull);
    if (tid == 0) resps[b * TSTEPS + t] = c;
    int k = tid * 4;
    float4 e = *(const float4*)&emb[(size_t)c * HD + k];
    float xs[4] = {e.x, e.y, e.z, e.w};
    s16x4 p1, p2;
    #pragma unroll
    for (int u = 0; u < 4; ++u) {
        short s1 = bf16bits(xs[u]);
        short s2 = bf16bits(xs[u] - bf16val(s1));
        p1[u] = s1; p2[u] = s2;
    }
    int bo = k * 2;
    char* xdst = (char*)(Xsp + (size_t)b * 2048);
    *(s16x4*)(xdst + SWZ(b, bo))        = p1;
    *(s16x4*)(xdst + SWZ(b, 2048 + bo)) = p2;
}

// ---------------- resp_lens ----------------
__global__ void resp_lens_kernel(const int* __restrict__ resps, int* __restrict__ lens)
{
    int b = threadIdx.x;
    if (b >= NB) return;
    int len = TSTEPS + 1;
    for (int t = TSTEPS - 1; t >= 0; t--)
        if (resps[b * TSTEPS + t] == 2) len = t + 1;
    lens[b] = len;
}

extern "C" void kernel_launch(void* const* d_in, const int* in_sizes, int n_in,
                              void* d_out, int out_size, void* d_ws, size_t ws_size,
                              hipStream_t stream) {
    const float* zs   = (const float*)d_in[0];
    const float* cs   = (const float*)d_in[1];
    const float* emb  = (const float*)d_in[2];
    const float* Wih  = (const float*)d_in[3];
    const float* Whh  = (const float*)d_in[4];
    const float* bih  = (const float*)d_in[5];
    const float* bhh  = (const float*)d_in[6];
    const float* Wout = (const float*)d_in[7];
    const float* bout = (const float*)d_in[8];
    int* out = (int*)d_out;  // [64*32 resps][64 lens], int32

    char* ws = (char*)d_ws;
    float4* ht4  = (float4*)ws; ws += (size_t)256 * NB * 16;          // 256 KB
    float*  gpart = (float*)ws; ws += (size_t)4 * NB * NC6 * 4;       // 6.3 MB
    short*  Hsp  = (short*)ws;  ws += (size_t)NB * 2048 * 2;          // 256 KB
    short*  Xsp  = (short*)ws;  ws += (size_t)NB * 2048 * 2;          // 256 KB
    float*  wnorm = (float*)ws; ws += (size_t)NV * 4;                 // 128 KB
    float*  hnorm = (float*)ws; ws += 256;
    float*  bmlow = (float*)ws; ws += (size_t)NB * BML * 4;           // 128 KB
    unsigned long long* best = (unsigned long long*)ws; ws += NB * 8;
    float*  lb   = (float*)ws;  ws += (size_t)NB * NV * 4;            // 8.2 MB
    short*  Wbf  = (short*)ws;  ws += (size_t)NV * HD * 2;            // 65.5 MB
    short*  WihSp = (short*)ws; ws += (size_t)H3 * 2048 * 2;          // 12.6 MB
    short*  WhhSp = (short*)ws; ws += (size_t)H3 * 2048 * 2;          // 12.6 MB

    wsplit2_kernel<<<NC6, 256, 0, stream>>>(Wih, Whh, WihSp, WhhSp);
    wbf_kernel<<<NV, 256, 0, stream>>>(Wout, Wbf, wnorm);
    init_kernel<<<NB, 256, 0, stream>>>(zs, cs, emb, ht4, Hsp, Xsp, hnorm, best);
    for (int t = 0; t < TSTEPS; t++) {
        gates_mfma<<<96 * 4, 256, 0, stream>>>(Xsp, Hsp, WihSp, WhhSp, gpart);
        gru_fuse<<<NB, 256, 0, stream>>>(gpart, bih, bhh, ht4, Hsp, hnorm, best);
        logits_lb<<<LBLK, 256, 0, stream>>>(Hsp, Wbf, bout, wnorm, hnorm, lb, bmlow);
        select2_kernel<<<NB * NSLICE, 256, 0, stream>>>(lb, wnorm, hnorm, bmlow,
                                                        Wout, bout, ht4, best);
        gather_kernel<<<NB, 256, 0, stream>>>(best, emb, out, t, Xsp);
    }
    resp_lens_kernel<<<1, 64, 0, stream>>>(out, out + NB * TSTEPS);
}